// Round 14
// baseline (236.287 us; speedup 1.0000x reference)
//
#include <hip/hip_runtime.h>
#include <hip/hip_bf16.h>

#define DI __device__ __forceinline__

constexpr int B_ = 16, N_ = 4096, C_ = 256, H_ = 4;
constexpr size_t QSZ = (size_t)4096 * 4096;   // elements in one [4096][4096] bf16 plane
constexpr int LDW = 72;    // LDS row stride (ushorts) for 64-wide bf16 tiles (bank-rotating)
constexpr int LDC = 136;   // LDS row stride (ushorts) for 128-wide epilogue tile (16B-aligned)

typedef __attribute__((ext_vector_type(8))) short bh8;
typedef __attribute__((ext_vector_type(4))) float fx4;
typedef __attribute__((address_space(1))) unsigned int gu32;
typedef __attribute__((address_space(3))) unsigned int lu32;

DI float bfu2f(unsigned short u) { return __uint_as_float(((unsigned)u) << 16); }
DI void bfu2x2(unsigned u, float& lo, float& hi) {
  lo = __uint_as_float(u << 16);
  hi = __uint_as_float(u & 0xffff0000u);
}
DI unsigned short f2bfu(float f) {   // RNE f32->bf16 (finite inputs)
  unsigned u = __float_as_uint(f);
  unsigned r = 0x7fffu + ((u >> 16) & 1u);
  return (unsigned short)((u + r) >> 16);
}
DI void gl_lds16(const unsigned short* g, unsigned short* l) {
  // async 16B/lane global->LDS; LDS dest = wave-uniform base + lane*16
  __builtin_amdgcn_global_load_lds((gu32*)g, (lu32*)l, 16, 0, 0);
}
// Co storage swizzle: logical (row, col) lives at octet (o&8)|((o&7)^((row>>3)&7)).
// De-aliases rows 8 apart so token-major scalar column reads (row = 8j + t,
// j = lane) spread across all 8 bank groups.
DI int co_off(int row, int col) {
  const int o = col >> 3;
  const int so = (o & 8) | ((o & 7) ^ ((row >> 3) & 7));
  return row * LDC + so * 8 + (col & 7);
}

// Wb layout (ushorts): Wq@0 (65536), Wkvv@65536 (196608), Wo2@262144 (32768),
// Wo1@294912 (32768). WE -> wEb [64][4096]. grid = 288.
__global__ __launch_bounds__(256) void cast_w(
    const float* __restrict__ Wq, const float* __restrict__ Wkvv,
    const float* __restrict__ Wo2, const float* __restrict__ Wo1,
    const float* __restrict__ WE, unsigned short* __restrict__ Wb,
    unsigned short* __restrict__ wEb)
{
  const int b = blockIdx.x;
  const float* src; unsigned short* dst; int lb;
  if (b < 32)       { src = Wq;   dst = Wb;          lb = b; }
  else if (b < 128) { src = Wkvv; dst = Wb + 65536;  lb = b - 32; }
  else if (b < 144) { src = Wo2;  dst = Wb + 262144; lb = b - 128; }
  else if (b < 160) { src = Wo1;  dst = Wb + 294912; lb = b - 144; }
  else              { src = WE;   dst = wEb;         lb = b - 160; }
  const size_t base = ((size_t)lb * 256 + threadIdx.x) * 8;
  const float4 a = *reinterpret_cast<const float4*>(&src[base]);
  const float4 bb = *reinterpret_cast<const float4*>(&src[base + 4]);
  union { uint4 v; unsigned short u[8]; } pk;
  pk.u[0] = f2bfu(a.x);  pk.u[1] = f2bfu(a.y);  pk.u[2] = f2bfu(a.z);  pk.u[3] = f2bfu(a.w);
  pk.u[4] = f2bfu(bb.x); pk.u[5] = f2bfu(bb.y); pk.u[6] = f2bfu(bb.z); pk.u[7] = f2bfu(bb.w);
  *reinterpret_cast<uint4*>(&dst[base]) = pk.v;
}

// ---------------------------------------------------------------------------
// Fused bf16 MFMA projection GEMM (q + kvv in one launch), reading fp32
// x/ref directly with a T14 async-STAGE split: REGLOAD(t+1) (fp32 global ->
// regs) issued BEFORE COMPUTE(t) so HBM/L2 latency hides under MFMA; the
// cvt + write-side-swizzled ds_write_b128 happens just before use. W staged
// bf16 via global_load_lds (re-issued post-compute; L2-hot). Ping-pong reg
// sets ra[2][8] with fully-unrolled t -> all static indices (rule #20).
// Single-buffer staging unioned with co_off-swizzled Co (35.3KB -> 4 blk/CU).
// blockIdx.y 0..1 -> q (qT + qtok); 2..7 -> kvv: k -> plane0, v_ca -> vtok
// only, v_sa -> plane1. grid = (32 ntiles, 8, 16 b), block = 256 (2x2 waves).
// ---------------------------------------------------------------------------
__global__ __launch_bounds__(256) void proj_fused(
    const float* __restrict__ xf, const float* __restrict__ reff,
    const unsigned short* __restrict__ Wball,
    const float* __restrict__ bq, const float* __restrict__ bkvv,
    unsigned short* __restrict__ qT, unsigned short* __restrict__ kvv2T,
    unsigned short* __restrict__ qtok, unsigned short* __restrict__ vtok)
{
  __shared__ unsigned short smem[17408];      // union: W[0..8191]+X[8192..16383]; Co[0..17407]
  __shared__ float biasS[128];
  const int tid = threadIdx.x;
  const int lane = tid & 63, wid = tid >> 6;
  const int l15 = lane & 15, l4 = lane >> 4;
  const int wr = wid >> 1, wc = wid & 1;
  const int yt = blockIdx.y;
  const bool isq = (yt < 2);
  const float* Af = isq ? xf : reff;
  const unsigned short* Wsrc = isq ? Wball : (Wball + 65536);
  const float* bias = isq ? bq : bkvv;
  unsigned short* outT = isq ? qT : kvv2T;
  const int j0 = (isq ? yt : (yt - 2)) * 128;
  const int pl = j0 >> 8;                       // kvv source plane 0..2 (q: 0)
  const bool writeT = isq || (pl != 1);         // skip channel-major for v_ca
  const int plT = (!isq && pl == 2) ? 1 : 0;    // compacted plane index
  unsigned short* tok = isq ? qtok : ((pl == 1) ? vtok : nullptr);
  const int n0 = blockIdx.x * 128;
  const int b = blockIdx.z;
  const size_t tok0 = (size_t)b * 4096 + n0;
  const int lrow = lane >> 3, lcb = lane & 7;
  if (tid < 128) biasS[tid] = bias[j0 + tid];

  fx4 acc[4][4];
#pragma unroll
  for (int m = 0; m < 4; ++m)
#pragma unroll
    for (int n = 0; n < 4; ++n) acc[m][n] = (fx4){0.f, 0.f, 0.f, 0.f};

  float4 ra[2][8];
  auto REGLOAD = [&](float4 (&rg)[8], int k0) {
#pragma unroll
    for (int i = 0; i < 4; ++i) {
      const int idx = i * 256 + tid;
      const int r = idx >> 3, o = idx & 7;
      const float* s = &Af[(tok0 + r) * 256 + k0 + o * 8];
      rg[2 * i]     = *reinterpret_cast<const float4*>(s);
      rg[2 * i + 1] = *reinterpret_cast<const float4*>(s + 4);
    }
  };
  auto XWRITE = [&](const float4 (&rg)[8]) {
    unsigned short* Xd = smem + 8192;
#pragma unroll
    for (int i = 0; i < 4; ++i) {
      const int idx = i * 256 + tid;
      const int r = idx >> 3, o = idx & 7;
      const float4 a0 = rg[2 * i], a1 = rg[2 * i + 1];
      union { uint4 v; unsigned short u[8]; } pk;
      pk.u[0] = f2bfu(a0.x); pk.u[1] = f2bfu(a0.y);
      pk.u[2] = f2bfu(a0.z); pk.u[3] = f2bfu(a0.w);
      pk.u[4] = f2bfu(a1.x); pk.u[5] = f2bfu(a1.y);
      pk.u[6] = f2bfu(a1.z); pk.u[7] = f2bfu(a1.w);
      *reinterpret_cast<uint4*>(&Xd[r * 64 + ((o ^ (r & 7)) << 3)]) = pk.v;
    }
  };
  auto WSTAGE = [&](int k0) {
    unsigned short* Wd = smem;
#pragma unroll
    for (int i = 0; i < 4; ++i) {
      const int ci = i * 4 + wid;            // chunk 0..15 (8 rows each)
      const int row = ci * 8 + lrow;         // 0..127
      const int scb = lcb ^ (row & 7);       // pre-swizzled source col-block
      gl_lds16(&Wsrc[(size_t)(j0 + row) * 256 + k0 + scb * 8], &Wd[ci * 512]);
    }
  };
  auto COMPUTE = [&]() {
    const unsigned short* Ws = smem;
    const unsigned short* Xs = smem + 8192;
#pragma unroll
    for (int kk = 0; kk < 2; ++kk) {
      const int cbi = kk * 4 + l4;           // col-block index 0..7
      bh8 af[4], bfr[4];
#pragma unroll
      for (int m = 0; m < 4; ++m) {
        const int r = wr * 64 + m * 16 + l15;
        af[m] = *reinterpret_cast<const bh8*>(&Ws[r * 64 + ((cbi ^ (r & 7)) << 3)]);
      }
#pragma unroll
      for (int n = 0; n < 4; ++n) {
        const int r = wc * 64 + n * 16 + l15;
        bfr[n] = *reinterpret_cast<const bh8*>(&Xs[r * 64 + ((cbi ^ (r & 7)) << 3)]);
      }
#pragma unroll
      for (int m = 0; m < 4; ++m)
#pragma unroll
        for (int n = 0; n < 4; ++n)
          acc[m][n] = __builtin_amdgcn_mfma_f32_16x16x32_bf16(af[m], bfr[n], acc[m][n], 0, 0, 0);
    }
  };

  REGLOAD(ra[0], 0);
  WSTAGE(0);
#pragma unroll
  for (int t = 0; t < 4; ++t) {
    XWRITE(ra[t & 1]);                       // cvt+ds_write current tile
    __syncthreads();                         // X(t) + W(t) resident
    if (t < 3) REGLOAD(ra[(t + 1) & 1], (t + 1) * 64);  // latency hides under MFMA
    COMPUTE();
    __syncthreads();                         // staging LDS free to overwrite
    if (t < 3) WSTAGE((t + 1) * 64);         // W(t+1) async; lands during next cvt
  }

  // epilogue: acc -> bf16 LDS [128][128] (stride LDC, co_off octet swizzle)
  unsigned short* Co = smem;
#pragma unroll
  for (int m = 0; m < 4; ++m) {
    const int jl = wr * 64 + m * 16 + (l4 << 2);
#pragma unroll
    for (int n = 0; n < 4; ++n) {
      const int col = wc * 64 + n * 16 + l15;
#pragma unroll
      for (int r = 0; r < 4; ++r) {
        const int row = jl + r;
        Co[co_off(row, col)] = f2bfu(acc[m][n][r] + biasS[row]);
      }
    }
  }
  __syncthreads();
  // channel-major store: 16 lanes x 16B = 256B contiguous per row, 16 rows/instr
  if (writeT) {
#pragma unroll
    for (int c = 0; c < 8; ++c) {
      const int r = c * 16 + (tid >> 4);
      const int colseg = (tid & 15) * 8;     // 16B-aligned logical octet
      const uint4 v = *reinterpret_cast<const uint4*>(&Co[co_off(r, colseg)]);
      const int jj = j0 + r;
      const int rowT = (plT * B_ + b) * 256 + (jj & 255);
      *reinterpret_cast<uint4*>(&outT[(size_t)rowT * N_ + n0 + colseg]) = v;
    }
  }
  // token-major store: 8 lanes fill one 128B token row; 32 rows = 4KB contig/instr.
  if (tok) {
    const int j = tid & 7;
#pragma unroll
    for (int i = 0; i < 8; ++i) {
      const int half = i >> 2;                 // channel half (64 ch each)
      const int cb = half * 64 + j * 8;
      const int nloc = (i & 3) * 32 + (tid >> 3);
      union { uint4 v; unsigned short u[8]; } pk;
#pragma unroll
      for (int t = 0; t < 8; ++t)
        pk.u[t] = Co[co_off(cb + t, nloc)];
      const int jj = j0 + cb;
      const int hh = (jj >> 6) & 3, cc = jj & 63;
      *reinterpret_cast<uint4*>(
          &tok[(((size_t)b * 4 + hh) * 4096 + n0 + nloc) * 64 + cc]) = pk.v;
    }
  }
}

// ---------------------------------------------------------------------------
// All-bf16 MFMA output GEMM, single-buffer staging (33KB LDS -> 4 blocks/CU).
// z=0: out[:, :128] = Asa @ Wo2^T + bo2 ; z=1: out[:, 128:] = Aca @ Wo1^T + bo1
// grid = (512, 1, 2), block = 256.
// ---------------------------------------------------------------------------
__global__ __launch_bounds__(256) void gemm_outm2(
    const unsigned short* __restrict__ Asa, const unsigned short* __restrict__ Aca,
    const unsigned short* __restrict__ Wob,
    const float* __restrict__ bo2, const float* __restrict__ bo1,
    float* __restrict__ out)
{
  __shared__ unsigned short smem[16384];
  __shared__ float biasS[128];
  const unsigned short* A = (blockIdx.z == 0) ? Asa : Aca;
  const unsigned short* Wsrc = Wob + (size_t)blockIdx.z * 32768;
  const float* bias = (blockIdx.z == 0) ? bo2 : bo1;
  const int joff = blockIdx.z * 128;
  const int tid = threadIdx.x;
  const int lane = tid & 63, wid = tid >> 6;
  const int l15 = lane & 15, l4 = lane >> 4;
  const int wr = wid >> 1, wc = wid & 1;
  const size_t m0 = (size_t)blockIdx.x * 128;
  const int lrow = lane >> 3, lcb = lane & 7;
  if (tid < 128) biasS[tid] = bias[tid];

  fx4 acc[4][4];
#pragma unroll
  for (int m = 0; m < 4; ++m)
#pragma unroll
    for (int n = 0; n < 4; ++n) acc[m][n] = (fx4){0.f, 0.f, 0.f, 0.f};

  auto STAGE = [&](int k0) {
    unsigned short* Wd = smem;
    unsigned short* Xd = smem + 8192;
#pragma unroll
    for (int i = 0; i < 4; ++i) {
      const int ci = i * 4 + wid;
      const int row = ci * 8 + lrow;
      const int scb = lcb ^ (row & 7);
      gl_lds16(&Wsrc[(size_t)row * 256 + k0 + scb * 8], &Wd[ci * 512]);
      gl_lds16(&A[(m0 + row) * 256 + k0 + scb * 8], &Xd[ci * 512]);
    }
  };
  auto COMPUTE = [&]() {
    const unsigned short* Ws = smem;
    const unsigned short* Xs = smem + 8192;
#pragma unroll
    for (int kk = 0; kk < 2; ++kk) {
      const int cbi = kk * 4 + l4;
      bh8 af[4], bfr[4];
#pragma unroll
      for (int m = 0; m < 4; ++m) {   // A-frag = tokens (D-row side)
        const int r = wr * 64 + m * 16 + l15;
        af[m] = *reinterpret_cast<const bh8*>(&Xs[r * 64 + ((cbi ^ (r & 7)) << 3)]);
      }
#pragma unroll
      for (int n = 0; n < 4; ++n) {   // B-frag = W (D-col side)
        const int r = wc * 64 + n * 16 + l15;
        bfr[n] = *reinterpret_cast<const bh8*>(&Ws[r * 64 + ((cbi ^ (r & 7)) << 3)]);
      }
#pragma unroll
      for (int m = 0; m < 4; ++m)
#pragma unroll
        for (int n = 0; n < 4; ++n)
          acc[m][n] = __builtin_amdgcn_mfma_f32_16x16x32_bf16(af[m], bfr[n], acc[m][n], 0, 0, 0);
    }
  };

  for (int t = 0; t < 4; ++t) {
    STAGE(t * 64);
    __syncthreads();
    COMPUTE();
    __syncthreads();
  }

#pragma unroll
  for (int mi = 0; mi < 4; ++mi) {
    const int mrow = wr * 64 + mi * 16 + (l4 << 2);
#pragma unroll
    for (int ni = 0; ni < 4; ++ni) {
      const int j = wc * 64 + ni * 16 + l15;
      const float bv = biasS[j];
#pragma unroll
      for (int r = 0; r < 4; ++r)
        out[(m0 + mrow + r) * 256 + joff + j] = acc[mi][ni][r] + bv;
    }
  }
}

// ---------------------------------------------------------------------------
// MFMA stats + fused norms. Per (bh, chunk of 512 tokens):
// wave0: S=q.k^T; wave1: KpT=WE.k^T; wave2: Vp=v.WE^T; wave3: stages + per-
// channel sum-of-squares of q,k over the chunk -> partN.
// part[chunk][bh][3][64][64]; partN[chunk][bh][2][64]. grid = (64,8), blk 256.
// ---------------------------------------------------------------------------
__global__ __launch_bounds__(256) void stats_mfma(
    const unsigned short* __restrict__ qT, const unsigned short* __restrict__ kT,
    const unsigned short* __restrict__ vT, const unsigned short* __restrict__ wEb,
    float* __restrict__ part, float* __restrict__ partN)
{
  __shared__ unsigned short smem[4 * 64 * LDW];
  unsigned short* sq = smem;
  unsigned short* sk = smem + 64 * LDW;
  unsigned short* sv = smem + 2 * 64 * LDW;
  unsigned short* sw = smem + 3 * 64 * LDW;
  const int tid = threadIdx.x;
  const int lane = tid & 63, wid = tid >> 6;
  const int bh = blockIdx.x, chunk = blockIdx.y;
  const size_t rowbase = (size_t)bh * 64 * N_;

  fx4 acc[4][4];
#pragma unroll
  for (int m = 0; m < 4; ++m)
#pragma unroll
    for (int n = 0; n < 4; ++n) acc[m][n] = (fx4){0.f, 0.f, 0.f, 0.f};
  float q2 = 0.f, k2 = 0.f;

  const unsigned short* Aop = (wid == 1) ? sw : (wid == 2) ? sv : sq;
  const unsigned short* Bop = (wid == 1) ? sk : (wid == 2) ? sw : sk;

  for (int tile = 0; tile < 8; ++tile) {
    const int n0 = chunk * 512 + tile * 64;
#pragma unroll
    for (int c = 0; c < 2; ++c) {
      const int idx = c * 256 + tid;       // 0..511
      const int r = idx >> 3;              // 0..63
      const int off = (idx & 7) * 8;       // 0..56
      *reinterpret_cast<uint4*>(&sq[r * LDW + off]) =
          *reinterpret_cast<const uint4*>(&qT[rowbase + (size_t)r * N_ + n0 + off]);
      *reinterpret_cast<uint4*>(&sk[r * LDW + off]) =
          *reinterpret_cast<const uint4*>(&kT[rowbase + (size_t)r * N_ + n0 + off]);
      *reinterpret_cast<uint4*>(&sv[r * LDW + off]) =
          *reinterpret_cast<const uint4*>(&vT[rowbase + (size_t)r * N_ + n0 + off]);
      *reinterpret_cast<uint4*>(&sw[r * LDW + off]) =
          *reinterpret_cast<const uint4*>(&wEb[(size_t)r * N_ + n0 + off]);
    }
    __syncthreads();
    if (wid < 3) {
#pragma unroll
      for (int kk = 0; kk < 2; ++kk) {
        const int kb = kk * 32 + (lane >> 4) * 8;
        bh8 af[4], bfr[4];
#pragma unroll
        for (int m = 0; m < 4; ++m)
          af[m] = *reinterpret_cast<const bh8*>(&Aop[(m * 16 + (lane & 15)) * LDW + kb]);
#pragma unroll
        for (int n = 0; n < 4; ++n)
          bfr[n] = *reinterpret_cast<const bh8*>(&Bop[(n * 16 + (lane & 15)) * LDW + kb]);
#pragma unroll
        for (int m = 0; m < 4; ++m)
#pragma unroll
          for (int n = 0; n < 4; ++n)
            acc[m][n] = __builtin_amdgcn_mfma_f32_16x16x32_bf16(af[m], bfr[n], acc[m][n], 0, 0, 0);
      }
    } else {
      // wave3: per-channel sum of squares for q and k (row = lane)
      const unsigned short* qrow = &sq[lane * LDW];
      const unsigned short* krow = &sk[lane * LDW];
#pragma unroll
      for (int t = 0; t < 8; ++t) {
        const uint4 uq = *reinterpret_cast<const uint4*>(&qrow[t * 8]);
        const uint4 uk = *reinterpret_cast<const uint4*>(&krow[t * 8]);
        float a, b;
        bfu2x2(uq.x, a, b); q2 += a * a + b * b;
        bfu2x2(uq.y, a, b); q2 += a * a + b * b;
        bfu2x2(uq.z, a, b); q2 += a * a + b * b;
        bfu2x2(uq.w, a, b); q2 += a * a + b * b;
        bfu2x2(uk.x, a, b); k2 += a * a + b * b;
        bfu2x2(uk.y, a, b); k2 += a * a + b * b;
        bfu2x2(uk.z, a, b); k2 += a * a + b * b;
        bfu2x2(uk.w, a, b); k2 += a * a + b * b;
      }
    }
    __syncthreads();
  }

  if (wid < 3) {
    float* base = &part[(((size_t)chunk * 64 + bh) * 3 + wid) * 4096];
#pragma unroll
    for (int m = 0; m < 4; ++m) {
      const int row0 = m * 16 + ((lane >> 4) << 2);
#pragma unroll
      for (int n = 0; n < 4; ++n) {
        const int col = n * 16 + (lane & 15);
#pragma unroll
        for (int r = 0; r < 4; ++r)
          base[(row0 + r) * 64 + col] = acc[m][n][r];
      }
    }
  } else {
    float* nb = &partN[((size_t)chunk * 64 + bh) * 128];
    nb[lane] = q2;
    nb[64 + lane] = k2;
  }
}

// ---------------------------------------------------------------------------
// Reduce partials (incl. norms); emit bf16 kp2t[p][c], vpb[d][p], and
// channel-attention softmax attn_b[bh][c][d]. grid = 64.
// ---------------------------------------------------------------------------
__global__ __launch_bounds__(256) void postproc_kernel(
    const float* __restrict__ part, const float* __restrict__ partN,
    const float* __restrict__ bE,
    const float* __restrict__ temp, const float* __restrict__ temp2,
    unsigned short* __restrict__ attn_b,
    unsigned short* __restrict__ kp2t, unsigned short* __restrict__ vpb)
{
  __shared__ float sums[12288];
  __shared__ float rqS[64], rkS[64];
  const int bh = blockIdx.x;
  const int tid = threadIdx.x;
  for (int idx = tid; idx < 12288; idx += 256) {
    float s = 0.f;
    for (int ch = 0; ch < 8; ++ch)
      s += part[((size_t)ch * 64 + bh) * 12288 + idx];
    sums[idx] = s;
  }
  if (tid < 128) {
    float s = 0.f;
    for (int ch = 0; ch < 8; ++ch)
      s += partN[((size_t)ch * 64 + bh) * 128 + tid];
    const float r = 1.f / fmaxf(sqrtf(s), 1e-12f);
    if (tid < 64) rqS[tid] = r; else rkS[tid - 64] = r;
  }
  __syncthreads();
  const float t2 = temp2[bh & 3];
  for (int idx = tid; idx < 4096; idx += 256) {
    const int p = idx >> 6, c = idx & 63;
    kp2t[(size_t)bh * 4096 + idx] =
        f2bfu((sums[4096 + idx] * rkS[c] + bE[p]) * rqS[c] * t2);
    vpb[(size_t)bh * 4096 + idx] = f2bfu(sums[8192 + idx] + bE[idx & 63]);
  }
  const float tv = temp[bh & 3];
  const int lane = tid & 63, wv = tid >> 6;
  for (int ri = 0; ri < 16; ++ri) {
    const int c = wv * 16 + ri;
    const float val = sums[c * 64 + lane] * rqS[c] * rkS[lane] * tv;
    float m = val;
#pragma unroll
    for (int off = 32; off > 0; off >>= 1) m = fmaxf(m, __shfl_xor(m, off));
    const float e = __expf(val - m);
    float ssum = e;
#pragma unroll
    for (int off = 32; off > 0; off >>= 1) ssum += __shfl_xor(ssum, off);
    attn_b[(size_t)bh * 4096 + c * 64 + lane] = f2bfu(e / ssum);   // [c][d]
  }
}

// ---------------------------------------------------------------------------
// MFMA spatial attention. Per wave: 64 tokens. GEMM1 S=q_tok·kp2t^T (K=c),
// in-register softmax over p, P(bf16)->LDS, GEMM2 out=P·vpb^T (K=p),
// transpose-store via stride-65 LDS to x_sa[b][d][h][n].
// grid = (64 bh, 16), block = 256 (4 waves).
// ---------------------------------------------------------------------------
__global__ __launch_bounds__(256) void sa_mfma(
    const unsigned short* __restrict__ qtok, const unsigned short* __restrict__ kp2t,
    const unsigned short* __restrict__ vpb, unsigned short* __restrict__ x_sa)
{
  __shared__ unsigned short skp[64 * LDW];
  __shared__ unsigned short svp[64 * LDW];
  __shared__ unsigned short pt[4][64 * LDW];
  const int tid = threadIdx.x;
  const int lane = tid & 63, wid = tid >> 6;
  const int l15 = lane & 15, l4 = lane >> 4;
  const int bh = blockIdx.x, b = bh >> 2, h = bh & 3;
  const int n0 = blockIdx.y * 256 + wid * 64;
  unsigned short* myp = &pt[wid][0];

#pragma unroll
  for (int i = 0; i < 2; ++i) {
    const int idx = i * 256 + tid;       // 0..511
    const int r = idx >> 3, off = (idx & 7) * 8;
    *reinterpret_cast<uint4*>(&skp[r * LDW + off]) =
        *reinterpret_cast<const uint4*>(&kp2t[(size_t)bh * 4096 + r * 64 + off]);
    *reinterpret_cast<uint4*>(&svp[r * LDW + off]) =
        *reinterpret_cast<const uint4*>(&vpb[(size_t)bh * 4096 + r * 64 + off]);
  }
  __syncthreads();

  // GEMM1: S[n][p]
  fx4 acc[4][4];
#pragma unroll
  for (int m = 0; m < 4; ++m)
#pragma unroll
    for (int j = 0; j < 4; ++j) acc[m][j] = (fx4){0.f, 0.f, 0.f, 0.f};
  const size_t qbase = ((size_t)bh * 4096 + n0) * 64;
#pragma unroll
  for (int kk = 0; kk < 2; ++kk) {
    const int kb = kk * 32 + l4 * 8;
    bh8 af[4], bf[4];
#pragma unroll
    for (int m = 0; m < 4; ++m)
      af[m] = *reinterpret_cast<const bh8*>(&qtok[qbase + (size_t)(m * 16 + l15) * 64 + kb]);
#pragma unroll
    for (int j = 0; j < 4; ++j)
      bf[j] = *reinterpret_cast<const bh8*>(&skp[(j * 16 + l15) * LDW + kb]);
#pragma unroll
    for (int m = 0; m < 4; ++m)
#pragma unroll
      for (int j = 0; j < 4; ++j)
        acc[m][j] = __builtin_amdgcn_mfma_f32_16x16x32_bf16(af[m], bf[j], acc[m][j], 0, 0, 0);
  }

  // softmax over p per row (row n = m*16 + l4*4 + r; col p = j*16 + l15)
  fx4 inv[4];
#pragma unroll
  for (int m = 0; m < 4; ++m) {
    fx4 vm = acc[m][0];
#pragma unroll
    for (int j = 1; j < 4; ++j)
#pragma unroll
      for (int r = 0; r < 4; ++r) vm[r] = fmaxf(vm[r], acc[m][j][r]);
#pragma unroll
    for (int msk = 1; msk < 16; msk <<= 1)
#pragma unroll
      for (int r = 0; r < 4; ++r) vm[r] = fmaxf(vm[r], __shfl_xor(vm[r], msk));
    fx4 s = (fx4){0.f, 0.f, 0.f, 0.f};
#pragma unroll
    for (int j = 0; j < 4; ++j)
#pragma unroll
      for (int r = 0; r < 4; ++r) {
        acc[m][j][r] = __expf(acc[m][j][r] - vm[r]);
        s[r] += acc[m][j][r];
      }
#pragma unroll
    for (int msk = 1; msk < 16; msk <<= 1)
#pragma unroll
      for (int r = 0; r < 4; ++r) s[r] += __shfl_xor(s[r], msk);
#pragma unroll
    for (int r = 0; r < 4; ++r) inv[m][r] = 1.f / s[r];
#pragma unroll
    for (int j = 0; j < 4; ++j)
#pragma unroll
      for (int r = 0; r < 4; ++r)
        myp[(m * 16 + l4 * 4 + r) * LDW + j * 16 + l15] = f2bfu(acc[m][j][r]);
  }

  // GEMM2: O[n][d] = P·vpb^T (per-wave private LDS; in-order DS, no barrier)
  fx4 acc2[4][4];
#pragma unroll
  for (int m = 0; m < 4; ++m)
#pragma unroll
    for (int j = 0; j < 4; ++j) acc2[m][j] = (fx4){0.f, 0.f, 0.f, 0.f};
#pragma unroll
  for (int kk = 0; kk < 2; ++kk) {
    const int kb = kk * 32 + l4 * 8;
    bh8 af[4], bf[4];
#pragma unroll
    for (int m = 0; m < 4; ++m)
      af[m] = *reinterpret_cast<const bh8*>(&myp[(m * 16 + l15) * LDW + kb]);
#pragma unroll
    for (int j = 0; j < 4; ++j)
      bf[j] = *reinterpret_cast<const bh8*>(&svp[(j * 16 + l15) * LDW + kb]);
#pragma unroll
    for (int m = 0; m < 4; ++m)
#pragma unroll
      for (int j = 0; j < 4; ++j)
        acc2[m][j] = __builtin_amdgcn_mfma_f32_16x16x32_bf16(af[m], bf[j], acc2[m][j], 0, 0, 0);
  }

  // epilogue: apply 1/sum per row, bf16 -> LDS [n][d] stride 65, store d-major
#pragma unroll
  for (int m = 0; m < 4; ++m)
#pragma unroll
    for (int j = 0; j < 4; ++j)
#pragma unroll
      for (int r = 0; r < 4; ++r)
        myp[(m * 16 + l4 * 4 + r) * 65 + j * 16 + l15] = f2bfu(acc2[m][j][r] * inv[m][r]);
#pragma unroll
  for (int dstep = 0; dstep < 8; ++dstep) {
    const int d = dstep * 8 + (lane >> 3);
    const int nseg = (lane & 7) * 8;
    union { uint4 v; unsigned short u[8]; } pk;
#pragma unroll
    for (int t = 0; t < 8; ++t) pk.u[t] = myp[(nseg + t) * 65 + d];
    *reinterpret_cast<uint4*>(
        &x_sa[((size_t)(b * 64 + d) * 4 + h) * (size_t)N_ + n0 + nseg]) = pk.v;
  }
}

// ---------------------------------------------------------------------------
// MFMA channel-attention apply: x_ca[n][c] = sum_d attn_b[c][d]*vtok[n][d].
// grid = (64 bh, 16), block = 256.
// ---------------------------------------------------------------------------
__global__ __launch_bounds__(256) void xca_mfma(
    const unsigned short* __restrict__ attn_b, const unsigned short* __restrict__ vtok,
    unsigned short* __restrict__ x_ca)
{
  __shared__ unsigned short co[4][64 * LDW];
  const int tid = threadIdx.x;
  const int lane = tid & 63, wid = tid >> 6;
  const int l15 = lane & 15, l4 = lane >> 4;
  const int bh = blockIdx.x, b = bh >> 2, h = bh & 3;
  const int n0 = blockIdx.y * 256 + wid * 64;
  unsigned short* myco = &co[wid][0];

  fx4 acc[4][4];
#pragma unroll
  for (int m = 0; m < 4; ++m)
#pragma unroll
    for (int j = 0; j < 4; ++j) acc[m][j] = (fx4){0.f, 0.f, 0.f, 0.f};
  const size_t abase = (size_t)bh * 4096;
  const size_t vbase = ((size_t)bh * 4096 + n0) * 64;
#pragma unroll
  for (int kk = 0; kk < 2; ++kk) {
    const int kb = kk * 32 + l4 * 8;
    bh8 af[4], bf[4];
#pragma unroll
    for (int m = 0; m < 4; ++m)   // A rows = c
      af[m] = *reinterpret_cast<const bh8*>(&attn_b[abase + (size_t)(m * 16 + l15) * 64 + kb]);
#pragma unroll
    for (int j = 0; j < 4; ++j)   // B rows = n
      bf[j] = *reinterpret_cast<const bh8*>(&vtok[vbase + (size_t)(j * 16 + l15) * 64 + kb]);
#pragma unroll
    for (int m = 0; m < 4; ++m)
#pragma unroll
      for (int j = 0; j < 4; ++j)
        acc[m][j] = __builtin_amdgcn_mfma_f32_16x16x32_bf16(af[m], bf[j], acc[m][j], 0, 0, 0);
  }

  // transpose via per-wave LDS: co[n][c], then coalesced store to x_ca[B,N,C]
#pragma unroll
  for (int m = 0; m < 4; ++m)
#pragma unroll
    for (int j = 0; j < 4; ++j)
#pragma unroll
      for (int r = 0; r < 4; ++r)
        myco[(j * 16 + l15) * LDW + m * 16 + l4 * 4 + r] = f2bfu(acc[m][j][r]);
#pragma unroll
  for (int p = 0; p < 8; ++p) {
    const int nloc = p * 8 + (lane >> 3);
    const int cseg = (lane & 7) * 8;
    const uint4 v = *reinterpret_cast<const uint4*>(&myco[nloc * LDW + cseg]);
    *reinterpret_cast<uint4*>(
        &x_ca[((size_t)b * N_ + n0 + nloc) * 256 + h * 64 + cseg]) = v;
  }
}

extern "C" void kernel_launch(void* const* d_in, const int* in_sizes, int n_in,
                              void* d_out, int out_size, void* d_ws, size_t ws_size,
                              hipStream_t stream)
{
  const float* x     = (const float*)d_in[0];
  const float* ref   = (const float*)d_in[1];
  const float* Wq    = (const float*)d_in[2];
  const float* bq    = (const float*)d_in[3];
  const float* Wkvv  = (const float*)d_in[4];
  const float* bkvv  = (const float*)d_in[5];
  const float* WE    = (const float*)d_in[6];
  const float* bE    = (const float*)d_in[7];
  const float* Wo1   = (const float*)d_in[8];
  const float* bo1   = (const float*)d_in[9];
  const float* Wo2   = (const float*)d_in[10];
  const float* bo2   = (const float*)d_in[11];
  const float* temp  = (const float*)d_in[12];
  const float* temp2 = (const float*)d_in[13];
  float* out = (float*)d_out;

  // ---- workspace plan (total ~237.9 MB; R5-proven budget 264 MB) ----
  char* ws = (char*)d_ws;
  unsigned short* qT      = (unsigned short*)(ws);             // [4096][4096] bf16
  unsigned short* kvv2T   = (unsigned short*)(ws + 33554432);  // [2][4096][4096] bf16 (k, v_sa)
  unsigned short* qtok    = (unsigned short*)(ws + 100663296); // [64bh][4096][64] bf16
  unsigned short* x_sa    = (unsigned short*)(ws + 134217728); // [B,hd,H,N] bf16
  unsigned short* vca_tok = (unsigned short*)(ws + 167772160); // [64bh][4096][64] bf16
  float*          part    = (float*)(ws + 201326592);          // [8][64][3][64][64] f32 (24 MB)
  unsigned short* x_ca    = (unsigned short*)(ws + 201326592); //  -> [B,N,C] bf16 (after postproc)
  float*          partN   = (float*)(ws + 226492416);          // [8][64][2][64] f32 (256 KB)
  unsigned short* Wb      = (unsigned short*)(ws + 234881024); // weights bf16 (655,360 B)
  unsigned short* wEb     = (unsigned short*)(ws + 235536384); // [64][4096] bf16
  unsigned short* attn_b  = (unsigned short*)(ws + 236093440); // [64bh][64c][64d] bf16
  unsigned short* kp2t    = (unsigned short*)(ws + 236617728); // [64bh][64p][64c] bf16
  unsigned short* vpb     = (unsigned short*)(ws + 237142016); // [64bh][64d][64p] bf16

  const dim3 blk(256);
  cast_w<<<dim3(288), blk, 0, stream>>>(Wq, Wkvv, Wo2, Wo1, WE, Wb, wEb);
  proj_fused<<<dim3(32, 8, 16), blk, 0, stream>>>(x, ref, Wb, bq, bkvv,
                                                  qT, kvv2T, qtok, vca_tok);
  stats_mfma<<<dim3(64, 8), blk, 0, stream>>>(qT, kvv2T, kvv2T + QSZ, wEb, part, partN);
  postproc_kernel<<<dim3(64), blk, 0, stream>>>(part, partN, bE, temp, temp2,
                                                attn_b, kp2t, vpb);
  sa_mfma<<<dim3(64, 16), blk, 0, stream>>>(qtok, kp2t, vpb, x_sa);
  xca_mfma<<<dim3(64, 16), blk, 0, stream>>>(attn_b, vca_tok, x_ca);
  gemm_outm2<<<dim3(512, 1, 2), blk, 0, stream>>>(x_sa, x_ca, Wb + 262144, bo2, bo1, out);
}

// Round 15
// 202.714 us; speedup vs baseline: 1.1656x; 1.1656x over previous
//
#include <hip/hip_runtime.h>
#include <hip/hip_bf16.h>

#define DI __device__ __forceinline__

constexpr int B_ = 16, N_ = 4096, C_ = 256, H_ = 4;
constexpr size_t QSZ = (size_t)4096 * 4096;   // elements in one [4096][4096] bf16 plane
constexpr int LDW = 72;    // LDS row stride (ushorts) for 64-wide bf16 tiles (bank-rotating)
constexpr int LDC = 136;   // LDS row stride (ushorts) for 128-wide epilogue tile (16B-aligned)

typedef __attribute__((ext_vector_type(8))) short bh8;
typedef __attribute__((ext_vector_type(4))) float fx4;
typedef __attribute__((address_space(1))) unsigned int gu32;
typedef __attribute__((address_space(3))) unsigned int lu32;

DI float bfu2f(unsigned short u) { return __uint_as_float(((unsigned)u) << 16); }
DI void bfu2x2(unsigned u, float& lo, float& hi) {
  lo = __uint_as_float(u << 16);
  hi = __uint_as_float(u & 0xffff0000u);
}
DI unsigned short f2bfu(float f) {   // RNE f32->bf16 (finite inputs)
  unsigned u = __float_as_uint(f);
  unsigned r = 0x7fffu + ((u >> 16) & 1u);
  return (unsigned short)((u + r) >> 16);
}
DI void gl_lds16(const unsigned short* g, unsigned short* l) {
  // async 16B/lane global->LDS; LDS dest = wave-uniform base + lane*16
  __builtin_amdgcn_global_load_lds((gu32*)g, (lu32*)l, 16, 0, 0);
}
// Co storage swizzle: logical (row, col) lives at octet (o&8)|((o&7)^((row>>3)&7)).
// De-aliases rows 8 apart so token-major scalar column reads (row = 8j + t,
// j = lane) spread across all 8 bank groups.
DI int co_off(int row, int col) {
  const int o = col >> 3;
  const int so = (o & 8) | ((o & 7) ^ ((row >> 3) & 7));
  return row * LDC + so * 8 + (col & 7);
}

// ---------------------------------------------------------------------------
// Merged fp32 -> bf16 cast: blocks 0..8191 x, 8192..16383 ref, 16384..16671
// weights (Wq/Wkvv/Wo2/Wo1/WE). One launch replaces cast_xref + cast_w.
// ---------------------------------------------------------------------------
__global__ __launch_bounds__(256) void cast_all(
    const float* __restrict__ x, const float* __restrict__ ref,
    const float* __restrict__ Wq, const float* __restrict__ Wkvv,
    const float* __restrict__ Wo2, const float* __restrict__ Wo1,
    const float* __restrict__ WE,
    unsigned short* __restrict__ xb, unsigned short* __restrict__ refb,
    unsigned short* __restrict__ Wb, unsigned short* __restrict__ wEb)
{
  const int bid = blockIdx.x;
  const float* src; unsigned short* dst; int lb;
  if (bid < 8192)       { src = x;    dst = xb;          lb = bid; }
  else if (bid < 16384) { src = ref;  dst = refb;        lb = bid - 8192; }
  else {
    const int b = bid - 16384;
    if (b < 32)       { src = Wq;   dst = Wb;          lb = b; }
    else if (b < 128) { src = Wkvv; dst = Wb + 65536;  lb = b - 32; }
    else if (b < 144) { src = Wo2;  dst = Wb + 262144; lb = b - 128; }
    else if (b < 160) { src = Wo1;  dst = Wb + 294912; lb = b - 144; }
    else              { src = WE;   dst = wEb;         lb = b - 160; }
  }
  const size_t base = ((size_t)lb * 256 + threadIdx.x) * 8;
  const float4 a = *reinterpret_cast<const float4*>(&src[base]);
  const float4 bb = *reinterpret_cast<const float4*>(&src[base + 4]);
  union { uint4 v; unsigned short u[8]; } pk;
  pk.u[0] = f2bfu(a.x);  pk.u[1] = f2bfu(a.y);  pk.u[2] = f2bfu(a.z);  pk.u[3] = f2bfu(a.w);
  pk.u[4] = f2bfu(bb.x); pk.u[5] = f2bfu(bb.y); pk.u[6] = f2bfu(bb.z); pk.u[7] = f2bfu(bb.w);
  *reinterpret_cast<uint4*>(&dst[base]) = pk.v;
}

// ---------------------------------------------------------------------------
// Fused bf16 MFMA projection GEMM (q + kvv in one launch). Single-buffer
// gl_lds staging unioned with the co_off-swizzled Co epilogue (35.3KB ->
// 4 blocks/CU). 1D grid with XCD-aware remap: the 8 y-slices sharing one
// A-tile get the same (lin & 7) residue -> same XCD L2 -> A re-reads hit L2.
// y 0..1 -> q (qT + qtok); 2..7 -> kvv: k -> plane0, v_ca -> vtok only,
// v_sa -> plane1. grid = 4096 blocks, block = 256 (2x2 waves).
// ---------------------------------------------------------------------------
__global__ __launch_bounds__(256) void proj_fused(
    const unsigned short* __restrict__ xb, const unsigned short* __restrict__ refb,
    const unsigned short* __restrict__ Wball,
    const float* __restrict__ bq, const float* __restrict__ bkvv,
    unsigned short* __restrict__ qT, unsigned short* __restrict__ kvv2T,
    unsigned short* __restrict__ qtok, unsigned short* __restrict__ vtok)
{
  __shared__ unsigned short smem[17408];      // union: staging W[0..8191]+X[8192..16383]; Co[0..17407]
  __shared__ float biasS[128];
  const int tid = threadIdx.x;
  const int lane = tid & 63, wid = tid >> 6;
  const int l15 = lane & 15, l4 = lane >> 4;
  const int wr = wid >> 1, wc = wid & 1;
  // XCD-aware decode: lin = ((G>>3)*8 + y)*8 + (G&7), G = xi + 32*zi
  const int lin = blockIdx.x;
  const int xcd = lin & 7;
  const int s = lin >> 3;
  const int yt = s & 7;
  const int G = (s >> 3) * 8 + xcd;
  const int xi = G & 31;                        // n-tile index
  const int b = G >> 5;                         // batch
  const bool isq = (yt < 2);
  const unsigned short* Ab = isq ? xb : refb;
  const unsigned short* Wsrc = isq ? Wball : (Wball + 65536);
  const float* bias = isq ? bq : bkvv;
  unsigned short* outT = isq ? qT : kvv2T;
  const int j0 = (isq ? yt : (yt - 2)) * 128;
  const int pl = j0 >> 8;                       // kvv source plane 0..2 (q: 0)
  const bool writeT = isq || (pl != 1);         // skip channel-major for v_ca
  const int plT = (!isq && pl == 2) ? 1 : 0;    // compacted plane index
  unsigned short* tok = isq ? qtok : ((pl == 1) ? vtok : nullptr);
  const int n0 = xi * 128;
  const size_t tok0 = (size_t)b * 4096 + n0;
  const int lrow = lane >> 3, lcb = lane & 7;
  if (tid < 128) biasS[tid] = bias[j0 + tid];

  fx4 acc[4][4];
#pragma unroll
  for (int m = 0; m < 4; ++m)
#pragma unroll
    for (int n = 0; n < 4; ++n) acc[m][n] = (fx4){0.f, 0.f, 0.f, 0.f};

  auto STAGE = [&](int k0) {
    unsigned short* Wd = smem;
    unsigned short* Xd = smem + 8192;
#pragma unroll
    for (int i = 0; i < 4; ++i) {
      const int ci = i * 4 + wid;            // chunk 0..15 (8 rows each)
      const int row = ci * 8 + lrow;         // 0..127
      const int scb = lcb ^ (row & 7);       // pre-swizzled source col-block
      gl_lds16(&Wsrc[(size_t)(j0 + row) * 256 + k0 + scb * 8], &Wd[ci * 512]);
      gl_lds16(&Ab[(tok0 + row) * 256 + k0 + scb * 8], &Xd[ci * 512]);
    }
  };
  auto COMPUTE = [&]() {
    const unsigned short* Ws = smem;
    const unsigned short* Xs = smem + 8192;
#pragma unroll
    for (int kk = 0; kk < 2; ++kk) {
      const int cbi = kk * 4 + l4;           // col-block index 0..7
      bh8 af[4], bfr[4];
#pragma unroll
      for (int m = 0; m < 4; ++m) {
        const int r = wr * 64 + m * 16 + l15;
        af[m] = *reinterpret_cast<const bh8*>(&Ws[r * 64 + ((cbi ^ (r & 7)) << 3)]);
      }
#pragma unroll
      for (int n = 0; n < 4; ++n) {
        const int r = wc * 64 + n * 16 + l15;
        bfr[n] = *reinterpret_cast<const bh8*>(&Xs[r * 64 + ((cbi ^ (r & 7)) << 3)]);
      }
#pragma unroll
      for (int m = 0; m < 4; ++m)
#pragma unroll
        for (int n = 0; n < 4; ++n)
          acc[m][n] = __builtin_amdgcn_mfma_f32_16x16x32_bf16(af[m], bfr[n], acc[m][n], 0, 0, 0);
    }
  };

  for (int t = 0; t < 4; ++t) {
    STAGE(t * 64);
    __syncthreads();                         // drains vmcnt: tile resident
    COMPUTE();
    __syncthreads();                         // reads done before next overwrite
  }

  // epilogue: acc -> bf16 LDS [128][128] (stride LDC, co_off octet swizzle)
  unsigned short* Co = smem;
#pragma unroll
  for (int m = 0; m < 4; ++m) {
    const int jl = wr * 64 + m * 16 + (l4 << 2);
#pragma unroll
    for (int n = 0; n < 4; ++n) {
      const int col = wc * 64 + n * 16 + l15;
#pragma unroll
      for (int r = 0; r < 4; ++r) {
        const int row = jl + r;
        Co[co_off(row, col)] = f2bfu(acc[m][n][r] + biasS[row]);
      }
    }
  }
  __syncthreads();
  // channel-major store: 16 lanes x 16B = 256B contiguous per row, 16 rows/instr
  if (writeT) {
#pragma unroll
    for (int c = 0; c < 8; ++c) {
      const int r = c * 16 + (tid >> 4);
      const int colseg = (tid & 15) * 8;     // 16B-aligned logical octet
      const uint4 v = *reinterpret_cast<const uint4*>(&Co[co_off(r, colseg)]);
      const int jj = j0 + r;
      const int rowT = (plT * B_ + b) * 256 + (jj & 255);
      *reinterpret_cast<uint4*>(&outT[(size_t)rowT * N_ + n0 + colseg]) = v;
    }
  }
  // token-major store: 8 lanes fill one 128B token row; 32 rows = 4KB contig/instr.
  // Scalar reads: row = cb+t with cb = (lane&7)*8 -> swizzle key (row>>3)&7 = lane&7
  // spreads the 8 octet-lanes across all 8 bank groups; static register index.
  if (tok) {
    const int j = tid & 7;
#pragma unroll
    for (int i = 0; i < 8; ++i) {
      const int half = i >> 2;                 // channel half (64 ch each)
      const int cb = half * 64 + j * 8;
      const int nloc = (i & 3) * 32 + (tid >> 3);
      union { uint4 v; unsigned short u[8]; } pk;
#pragma unroll
      for (int t = 0; t < 8; ++t)
        pk.u[t] = Co[co_off(cb + t, nloc)];
      const int jj = j0 + cb;
      const int hh = (jj >> 6) & 3, cc = jj & 63;
      *reinterpret_cast<uint4*>(
          &tok[(((size_t)b * 4 + hh) * 4096 + n0 + nloc) * 64 + cc]) = pk.v;
    }
  }
}

// ---------------------------------------------------------------------------
// All-bf16 MFMA output GEMM, single-buffer staging (33KB LDS -> 4 blocks/CU).
// z=0: out[:, :128] = Asa @ Wo2^T + bo2 ; z=1: out[:, 128:] = Aca @ Wo1^T + bo1
// grid = (512, 1, 2), block = 256.
// ---------------------------------------------------------------------------
__global__ __launch_bounds__(256) void gemm_outm2(
    const unsigned short* __restrict__ Asa, const unsigned short* __restrict__ Aca,
    const unsigned short* __restrict__ Wob,
    const float* __restrict__ bo2, const float* __restrict__ bo1,
    float* __restrict__ out)
{
  __shared__ unsigned short smem[16384];
  __shared__ float biasS[128];
  const unsigned short* A = (blockIdx.z == 0) ? Asa : Aca;
  const unsigned short* Wsrc = Wob + (size_t)blockIdx.z * 32768;
  const float* bias = (blockIdx.z == 0) ? bo2 : bo1;
  const int joff = blockIdx.z * 128;
  const int tid = threadIdx.x;
  const int lane = tid & 63, wid = tid >> 6;
  const int l15 = lane & 15, l4 = lane >> 4;
  const int wr = wid >> 1, wc = wid & 1;
  const size_t m0 = (size_t)blockIdx.x * 128;
  const int lrow = lane >> 3, lcb = lane & 7;
  if (tid < 128) biasS[tid] = bias[tid];

  fx4 acc[4][4];
#pragma unroll
  for (int m = 0; m < 4; ++m)
#pragma unroll
    for (int n = 0; n < 4; ++n) acc[m][n] = (fx4){0.f, 0.f, 0.f, 0.f};

  auto STAGE = [&](int k0) {
    unsigned short* Wd = smem;
    unsigned short* Xd = smem + 8192;
#pragma unroll
    for (int i = 0; i < 4; ++i) {
      const int ci = i * 4 + wid;
      const int row = ci * 8 + lrow;
      const int scb = lcb ^ (row & 7);
      gl_lds16(&Wsrc[(size_t)row * 256 + k0 + scb * 8], &Wd[ci * 512]);
      gl_lds16(&A[(m0 + row) * 256 + k0 + scb * 8], &Xd[ci * 512]);
    }
  };
  auto COMPUTE = [&]() {
    const unsigned short* Ws = smem;
    const unsigned short* Xs = smem + 8192;
#pragma unroll
    for (int kk = 0; kk < 2; ++kk) {
      const int cbi = kk * 4 + l4;
      bh8 af[4], bfr[4];
#pragma unroll
      for (int m = 0; m < 4; ++m) {   // A-frag = tokens (D-row side)
        const int r = wr * 64 + m * 16 + l15;
        af[m] = *reinterpret_cast<const bh8*>(&Xs[r * 64 + ((cbi ^ (r & 7)) << 3)]);
      }
#pragma unroll
      for (int n = 0; n < 4; ++n) {   // B-frag = W (D-col side)
        const int r = wc * 64 + n * 16 + l15;
        bfr[n] = *reinterpret_cast<const bh8*>(&Ws[r * 64 + ((cbi ^ (r & 7)) << 3)]);
      }
#pragma unroll
      for (int m = 0; m < 4; ++m)
#pragma unroll
        for (int n = 0; n < 4; ++n)
          acc[m][n] = __builtin_amdgcn_mfma_f32_16x16x32_bf16(af[m], bfr[n], acc[m][n], 0, 0, 0);
    }
  };

  for (int t = 0; t < 4; ++t) {
    STAGE(t * 64);
    __syncthreads();
    COMPUTE();
    __syncthreads();
  }

#pragma unroll
  for (int mi = 0; mi < 4; ++mi) {
    const int mrow = wr * 64 + mi * 16 + (l4 << 2);
#pragma unroll
    for (int ni = 0; ni < 4; ++ni) {
      const int j = wc * 64 + ni * 16 + l15;
      const float bv = biasS[j];
#pragma unroll
      for (int r = 0; r < 4; ++r)
        out[(m0 + mrow + r) * 256 + joff + j] = acc[mi][ni][r] + bv;
    }
  }
}

// ---------------------------------------------------------------------------
// MFMA stats + fused norms. Per (bh, chunk of 512 tokens):
// wave0: S=q.k^T; wave1: KpT=WE.k^T; wave2: Vp=v.WE^T; wave3: stages + per-
// channel sum-of-squares of q,k over the chunk -> partN.
// part[chunk][bh][3][64][64]; partN[chunk][bh][2][64]. grid = (64,8), blk 256.
// ---------------------------------------------------------------------------
__global__ __launch_bounds__(256) void stats_mfma(
    const unsigned short* __restrict__ qT, const unsigned short* __restrict__ kT,
    const unsigned short* __restrict__ vT, const unsigned short* __restrict__ wEb,
    float* __restrict__ part, float* __restrict__ partN)
{
  __shared__ unsigned short smem[4 * 64 * LDW];
  unsigned short* sq = smem;
  unsigned short* sk = smem + 64 * LDW;
  unsigned short* sv = smem + 2 * 64 * LDW;
  unsigned short* sw = smem + 3 * 64 * LDW;
  const int tid = threadIdx.x;
  const int lane = tid & 63, wid = tid >> 6;
  const int bh = blockIdx.x, chunk = blockIdx.y;
  const size_t rowbase = (size_t)bh * 64 * N_;

  fx4 acc[4][4];
#pragma unroll
  for (int m = 0; m < 4; ++m)
#pragma unroll
    for (int n = 0; n < 4; ++n) acc[m][n] = (fx4){0.f, 0.f, 0.f, 0.f};
  float q2 = 0.f, k2 = 0.f;

  const unsigned short* Aop = (wid == 1) ? sw : (wid == 2) ? sv : sq;
  const unsigned short* Bop = (wid == 1) ? sk : (wid == 2) ? sw : sk;

  for (int tile = 0; tile < 8; ++tile) {
    const int n0 = chunk * 512 + tile * 64;
#pragma unroll
    for (int c = 0; c < 2; ++c) {
      const int idx = c * 256 + tid;       // 0..511
      const int r = idx >> 3;              // 0..63
      const int off = (idx & 7) * 8;       // 0..56
      *reinterpret_cast<uint4*>(&sq[r * LDW + off]) =
          *reinterpret_cast<const uint4*>(&qT[rowbase + (size_t)r * N_ + n0 + off]);
      *reinterpret_cast<uint4*>(&sk[r * LDW + off]) =
          *reinterpret_cast<const uint4*>(&kT[rowbase + (size_t)r * N_ + n0 + off]);
      *reinterpret_cast<uint4*>(&sv[r * LDW + off]) =
          *reinterpret_cast<const uint4*>(&vT[rowbase + (size_t)r * N_ + n0 + off]);
      *reinterpret_cast<uint4*>(&sw[r * LDW + off]) =
          *reinterpret_cast<const uint4*>(&wEb[(size_t)r * N_ + n0 + off]);
    }
    __syncthreads();
    if (wid < 3) {
#pragma unroll
      for (int kk = 0; kk < 2; ++kk) {
        const int kb = kk * 32 + (lane >> 4) * 8;
        bh8 af[4], bfr[4];
#pragma unroll
        for (int m = 0; m < 4; ++m)
          af[m] = *reinterpret_cast<const bh8*>(&Aop[(m * 16 + (lane & 15)) * LDW + kb]);
#pragma unroll
        for (int n = 0; n < 4; ++n)
          bfr[n] = *reinterpret_cast<const bh8*>(&Bop[(n * 16 + (lane & 15)) * LDW + kb]);
#pragma unroll
        for (int m = 0; m < 4; ++m)
#pragma unroll
          for (int n = 0; n < 4; ++n)
            acc[m][n] = __builtin_amdgcn_mfma_f32_16x16x32_bf16(af[m], bfr[n], acc[m][n], 0, 0, 0);
      }
    } else {
      // wave3: per-channel sum of squares for q and k (row = lane)
      const unsigned short* qrow = &sq[lane * LDW];
      const unsigned short* krow = &sk[lane * LDW];
#pragma unroll
      for (int t = 0; t < 8; ++t) {
        const uint4 uq = *reinterpret_cast<const uint4*>(&qrow[t * 8]);
        const uint4 uk = *reinterpret_cast<const uint4*>(&krow[t * 8]);
        float a, b;
        bfu2x2(uq.x, a, b); q2 += a * a + b * b;
        bfu2x2(uq.y, a, b); q2 += a * a + b * b;
        bfu2x2(uq.z, a, b); q2 += a * a + b * b;
        bfu2x2(uq.w, a, b); q2 += a * a + b * b;
        bfu2x2(uk.x, a, b); k2 += a * a + b * b;
        bfu2x2(uk.y, a, b); k2 += a * a + b * b;
        bfu2x2(uk.z, a, b); k2 += a * a + b * b;
        bfu2x2(uk.w, a, b); k2 += a * a + b * b;
      }
    }
    __syncthreads();
  }

  if (wid < 3) {
    float* base = &part[(((size_t)chunk * 64 + bh) * 3 + wid) * 4096];
#pragma unroll
    for (int m = 0; m < 4; ++m) {
      const int row0 = m * 16 + ((lane >> 4) << 2);
#pragma unroll
      for (int n = 0; n < 4; ++n) {
        const int col = n * 16 + (lane & 15);
#pragma unroll
        for (int r = 0; r < 4; ++r)
          base[(row0 + r) * 64 + col] = acc[m][n][r];
      }
    }
  } else {
    float* nb = &partN[((size_t)chunk * 64 + bh) * 128];
    nb[lane] = q2;
    nb[64 + lane] = k2;
  }
}

// ---------------------------------------------------------------------------
// Reduce partials (incl. norms); emit bf16 kp2t[p][c], vpb[d][p], and
// channel-attention softmax attn_b[bh][c][d]. grid = 64.
// ---------------------------------------------------------------------------
__global__ __launch_bounds__(256) void postproc_kernel(
    const float* __restrict__ part, const float* __restrict__ partN,
    const float* __restrict__ bE,
    const float* __restrict__ temp, const float* __restrict__ temp2,
    unsigned short* __restrict__ attn_b,
    unsigned short* __restrict__ kp2t, unsigned short* __restrict__ vpb)
{
  __shared__ float sums[12288];
  __shared__ float rqS[64], rkS[64];
  const int bh = blockIdx.x;
  const int tid = threadIdx.x;
  for (int idx = tid; idx < 12288; idx += 256) {
    float s = 0.f;
    for (int ch = 0; ch < 8; ++ch)
      s += part[((size_t)ch * 64 + bh) * 12288 + idx];
    sums[idx] = s;
  }
  if (tid < 128) {
    float s = 0.f;
    for (int ch = 0; ch < 8; ++ch)
      s += partN[((size_t)ch * 64 + bh) * 128 + tid];
    const float r = 1.f / fmaxf(sqrtf(s), 1e-12f);
    if (tid < 64) rqS[tid] = r; else rkS[tid - 64] = r;
  }
  __syncthreads();
  const float t2 = temp2[bh & 3];
  for (int idx = tid; idx < 4096; idx += 256) {
    const int p = idx >> 6, c = idx & 63;
    kp2t[(size_t)bh * 4096 + idx] =
        f2bfu((sums[4096 + idx] * rkS[c] + bE[p]) * rqS[c] * t2);
    vpb[(size_t)bh * 4096 + idx] = f2bfu(sums[8192 + idx] + bE[idx & 63]);
  }
  const float tv = temp[bh & 3];
  const int lane = tid & 63, wv = tid >> 6;
  for (int ri = 0; ri < 16; ++ri) {
    const int c = wv * 16 + ri;
    const float val = sums[c * 64 + lane] * rqS[c] * rkS[lane] * tv;
    float m = val;
#pragma unroll
    for (int off = 32; off > 0; off >>= 1) m = fmaxf(m, __shfl_xor(m, off));
    const float e = __expf(val - m);
    float ssum = e;
#pragma unroll
    for (int off = 32; off > 0; off >>= 1) ssum += __shfl_xor(ssum, off);
    attn_b[(size_t)bh * 4096 + c * 64 + lane] = f2bfu(e / ssum);   // [c][d]
  }
}

// ---------------------------------------------------------------------------
// MFMA spatial attention. Per wave: 64 tokens. GEMM1 S=q_tok·kp2t^T (K=c),
// in-register softmax over p, P(bf16)->LDS, GEMM2 out=P·vpb^T (K=p),
// transpose-store via stride-65 LDS to x_sa[b][d][h][n].
// grid = (64 bh, 16), block = 256 (4 waves).
// ---------------------------------------------------------------------------
__global__ __launch_bounds__(256) void sa_mfma(
    const unsigned short* __restrict__ qtok, const unsigned short* __restrict__ kp2t,
    const unsigned short* __restrict__ vpb, unsigned short* __restrict__ x_sa)
{
  __shared__ unsigned short skp[64 * LDW];
  __shared__ unsigned short svp[64 * LDW];
  __shared__ unsigned short pt[4][64 * LDW];
  const int tid = threadIdx.x;
  const int lane = tid & 63, wid = tid >> 6;
  const int l15 = lane & 15, l4 = lane >> 4;
  const int bh = blockIdx.x, b = bh >> 2, h = bh & 3;
  const int n0 = blockIdx.y * 256 + wid * 64;
  unsigned short* myp = &pt[wid][0];

#pragma unroll
  for (int i = 0; i < 2; ++i) {
    const int idx = i * 256 + tid;       // 0..511
    const int r = idx >> 3, off = (idx & 7) * 8;
    *reinterpret_cast<uint4*>(&skp[r * LDW + off]) =
        *reinterpret_cast<const uint4*>(&kp2t[(size_t)bh * 4096 + r * 64 + off]);
    *reinterpret_cast<uint4*>(&svp[r * LDW + off]) =
        *reinterpret_cast<const uint4*>(&vpb[(size_t)bh * 4096 + r * 64 + off]);
  }
  __syncthreads();

  // GEMM1: S[n][p]
  fx4 acc[4][4];
#pragma unroll
  for (int m = 0; m < 4; ++m)
#pragma unroll
    for (int j = 0; j < 4; ++j) acc[m][j] = (fx4){0.f, 0.f, 0.f, 0.f};
  const size_t qbase = ((size_t)bh * 4096 + n0) * 64;
#pragma unroll
  for (int kk = 0; kk < 2; ++kk) {
    const int kb = kk * 32 + l4 * 8;
    bh8 af[4], bf[4];
#pragma unroll
    for (int m = 0; m < 4; ++m)
      af[m] = *reinterpret_cast<const bh8*>(&qtok[qbase + (size_t)(m * 16 + l15) * 64 + kb]);
#pragma unroll
    for (int j = 0; j < 4; ++j)
      bf[j] = *reinterpret_cast<const bh8*>(&skp[(j * 16 + l15) * LDW + kb]);
#pragma unroll
    for (int m = 0; m < 4; ++m)
#pragma unroll
      for (int j = 0; j < 4; ++j)
        acc[m][j] = __builtin_amdgcn_mfma_f32_16x16x32_bf16(af[m], bf[j], acc[m][j], 0, 0, 0);
  }

  // softmax over p per row (row n = m*16 + l4*4 + r; col p = j*16 + l15)
  fx4 inv[4];
#pragma unroll
  for (int m = 0; m < 4; ++m) {
    fx4 vm = acc[m][0];
#pragma unroll
    for (int j = 1; j < 4; ++j)
#pragma unroll
      for (int r = 0; r < 4; ++r) vm[r] = fmaxf(vm[r], acc[m][j][r]);
#pragma unroll
    for (int msk = 1; msk < 16; msk <<= 1)
#pragma unroll
      for (int r = 0; r < 4; ++r) vm[r] = fmaxf(vm[r], __shfl_xor(vm[r], msk));
    fx4 s = (fx4){0.f, 0.f, 0.f, 0.f};
#pragma unroll
    for (int j = 0; j < 4; ++j)
#pragma unroll
      for (int r = 0; r < 4; ++r) {
        acc[m][j][r] = __expf(acc[m][j][r] - vm[r]);
        s[r] += acc[m][j][r];
      }
#pragma unroll
    for (int msk = 1; msk < 16; msk <<= 1)
#pragma unroll
      for (int r = 0; r < 4; ++r) s[r] += __shfl_xor(s[r], msk);
#pragma unroll
    for (int r = 0; r < 4; ++r) inv[m][r] = 1.f / s[r];
#pragma unroll
    for (int j = 0; j < 4; ++j)
#pragma unroll
      for (int r = 0; r < 4; ++r)
        myp[(m * 16 + l4 * 4 + r) * LDW + j * 16 + l15] = f2bfu(acc[m][j][r]);
  }

  // GEMM2: O[n][d] = P·vpb^T (per-wave private LDS; in-order DS, no barrier)
  fx4 acc2[4][4];
#pragma unroll
  for (int m = 0; m < 4; ++m)
#pragma unroll
    for (int j = 0; j < 4; ++j) acc2[m][j] = (fx4){0.f, 0.f, 0.f, 0.f};
#pragma unroll
  for (int kk = 0; kk < 2; ++kk) {
    const int kb = kk * 32 + l4 * 8;
    bh8 af[4], bf[4];
#pragma unroll
    for (int m = 0; m < 4; ++m)
      af[m] = *reinterpret_cast<const bh8*>(&myp[(m * 16 + l15) * LDW + kb]);
#pragma unroll
    for (int j = 0; j < 4; ++j)
      bf[j] = *reinterpret_cast<const bh8*>(&svp[(j * 16 + l15) * LDW + kb]);
#pragma unroll
    for (int m = 0; m < 4; ++m)
#pragma unroll
      for (int j = 0; j < 4; ++j)
        acc2[m][j] = __builtin_amdgcn_mfma_f32_16x16x32_bf16(af[m], bf[j], acc2[m][j], 0, 0, 0);
  }

  // epilogue: apply 1/sum per row, bf16 -> LDS [n][d] stride 65, store d-major
#pragma unroll
  for (int m = 0; m < 4; ++m)
#pragma unroll
    for (int j = 0; j < 4; ++j)
#pragma unroll
      for (int r = 0; r < 4; ++r)
        myp[(m * 16 + l4 * 4 + r) * 65 + j * 16 + l15] = f2bfu(acc2[m][j][r] * inv[m][r]);
#pragma unroll
  for (int dstep = 0; dstep < 8; ++dstep) {
    const int d = dstep * 8 + (lane >> 3);
    const int nseg = (lane & 7) * 8;
    union { uint4 v; unsigned short u[8]; } pk;
#pragma unroll
    for (int t = 0; t < 8; ++t) pk.u[t] = myp[(nseg + t) * 65 + d];
    *reinterpret_cast<uint4*>(
        &x_sa[((size_t)(b * 64 + d) * 4 + h) * (size_t)N_ + n0 + nseg]) = pk.v;
  }
}

// ---------------------------------------------------------------------------
// MFMA channel-attention apply: x_ca[n][c] = sum_d attn_b[c][d]*vtok[n][d].
// grid = (64 bh, 16), block = 256.
// ---------------------------------------------------------------------------
__global__ __launch_bounds__(256) void xca_mfma(
    const unsigned short* __restrict__ attn_b, const unsigned short* __restrict__ vtok,
    unsigned short* __restrict__ x_ca)
{
  __shared__ unsigned short co[4][64 * LDW];
  const int tid = threadIdx.x;
  const int lane = tid & 63, wid = tid >> 6;
  const int l15 = lane & 15, l4 = lane >> 4;
  const int bh = blockIdx.x, b = bh >> 2, h = bh & 3;
  const int n0 = blockIdx.y * 256 + wid * 64;
  unsigned short* myco = &co[wid][0];

  fx4 acc[4][4];
#pragma unroll
  for (int m = 0; m < 4; ++m)
#pragma unroll
    for (int j = 0; j < 4; ++j) acc[m][j] = (fx4){0.f, 0.f, 0.f, 0.f};
  const size_t abase = (size_t)bh * 4096;
  const size_t vbase = ((size_t)bh * 4096 + n0) * 64;
#pragma unroll
  for (int kk = 0; kk < 2; ++kk) {
    const int kb = kk * 32 + l4 * 8;
    bh8 af[4], bf[4];
#pragma unroll
    for (int m = 0; m < 4; ++m)   // A rows = c
      af[m] = *reinterpret_cast<const bh8*>(&attn_b[abase + (size_t)(m * 16 + l15) * 64 + kb]);
#pragma unroll
    for (int j = 0; j < 4; ++j)   // B rows = n
      bf[j] = *reinterpret_cast<const bh8*>(&vtok[vbase + (size_t)(j * 16 + l15) * 64 + kb]);
#pragma unroll
    for (int m = 0; m < 4; ++m)
#pragma unroll
      for (int j = 0; j < 4; ++j)
        acc[m][j] = __builtin_amdgcn_mfma_f32_16x16x32_bf16(af[m], bf[j], acc[m][j], 0, 0, 0);
  }

  // transpose via per-wave LDS: co[n][c], then coalesced store to x_ca[B,N,C]
#pragma unroll
  for (int m = 0; m < 4; ++m)
#pragma unroll
    for (int j = 0; j < 4; ++j)
#pragma unroll
      for (int r = 0; r < 4; ++r)
        myco[(j * 16 + l15) * LDW + m * 16 + l4 * 4 + r] = f2bfu(acc[m][j][r]);
#pragma unroll
  for (int p = 0; p < 8; ++p) {
    const int nloc = p * 8 + (lane >> 3);
    const int cseg = (lane & 7) * 8;
    const uint4 v = *reinterpret_cast<const uint4*>(&myco[nloc * LDW + cseg]);
    *reinterpret_cast<uint4*>(
        &x_ca[((size_t)b * N_ + n0 + nloc) * 256 + h * 64 + cseg]) = v;
  }
}

extern "C" void kernel_launch(void* const* d_in, const int* in_sizes, int n_in,
                              void* d_out, int out_size, void* d_ws, size_t ws_size,
                              hipStream_t stream)
{
  const float* x     = (const float*)d_in[0];
  const float* ref   = (const float*)d_in[1];
  const float* Wq    = (const float*)d_in[2];
  const float* bq    = (const float*)d_in[3];
  const float* Wkvv  = (const float*)d_in[4];
  const float* bkvv  = (const float*)d_in[5];
  const float* WE    = (const float*)d_in[6];
  const float* bE    = (const float*)d_in[7];
  const float* Wo1   = (const float*)d_in[8];
  const float* bo1   = (const float*)d_in[9];
  const float* Wo2   = (const float*)d_in[10];
  const float* bo2   = (const float*)d_in[11];
  const float* temp  = (const float*)d_in[12];
  const float* temp2 = (const float*)d_in[13];
  float* out = (float*)d_out;

  // ---- workspace plan (R12-proven layout, ~237.9 MB) ----
  char* ws = (char*)d_ws;
  unsigned short* qT      = (unsigned short*)(ws);             // [4096][4096] bf16
  unsigned short* kvv2T   = (unsigned short*)(ws + 33554432);  // [2][4096][4096] bf16 (k, v_sa)
  unsigned short* qtok    = (unsigned short*)(ws + 100663296); // [64bh][4096][64] bf16
  unsigned short* refb    = (unsigned short*)(ws + 134217728); // ref bf16 (dead after proj)
  unsigned short* x_sa    = (unsigned short*)(ws + 134217728); //  -> [B,hd,H,N] bf16
  unsigned short* vca_tok = (unsigned short*)(ws + 167772160); // [64bh][4096][64] bf16
  unsigned short* xb      = (unsigned short*)(ws + 201326592); // x bf16 (dead after proj)
  float*          part    = (float*)(ws + 201326592);          //  -> [8][64][3][64][64] f32 (24 MB)
  unsigned short* x_ca    = (unsigned short*)(ws + 201326592); //  -> [B,N,C] bf16
  float*          partN   = (float*)(ws + 226492416);          // [8][64][2][64] f32 (256 KB)
  unsigned short* Wb      = (unsigned short*)(ws + 234881024); // weights bf16 (655,360 B)
  unsigned short* wEb     = (unsigned short*)(ws + 235536384); // [64][4096] bf16
  unsigned short* attn_b  = (unsigned short*)(ws + 236093440); // [64bh][64c][64d] bf16
  unsigned short* kp2t    = (unsigned short*)(ws + 236617728); // [64bh][64p][64c] bf16
  unsigned short* vpb     = (unsigned short*)(ws + 237142016); // [64bh][64d][64p] bf16

  const dim3 blk(256);
  cast_all<<<dim3(16672), blk, 0, stream>>>(x, ref, Wq, Wkvv, Wo2, Wo1, WE,
                                            xb, refb, Wb, wEb);
  proj_fused<<<dim3(4096), blk, 0, stream>>>(xb, refb, Wb, bq, bkvv,
                                             qT, kvv2T, qtok, vca_tok);
  stats_mfma<<<dim3(64, 8), blk, 0, stream>>>(qT, kvv2T, kvv2T + QSZ, wEb, part, partN);
  postproc_kernel<<<dim3(64), blk, 0, stream>>>(part, partN, bE, temp, temp2,
                                                attn_b, kp2t, vpb);
  sa_mfma<<<dim3(64, 16), blk, 0, stream>>>(qtok, kp2t, vpb, x_sa);
  xca_mfma<<<dim3(64, 16), blk, 0, stream>>>(attn_b, vca_tok, x_ca);
  gemm_outm2<<<dim3(512, 1, 2), blk, 0, stream>>>(x_sa, x_ca, Wb + 262144, bo2, bo1, out);
}